// Round 13
// baseline (146.822 us; speedup 1.0000x reference)
//
#include <hip/hip_runtime.h>

// FANS: B=131072 rows x 16 states, MLP 12->64->64->1 with tanh, fp32 in/out.
// R13 = unbundle R12. R12 post-mortem: poly tanh RAISED VALUBusy 65->83% and
// dur 82.7->90 — exp2/rcp run on the transcendental pipe which overlaps with
// main VALU issue; polynomializing moved idle-pipe work onto the saturated
// pipe. But R12's OTHER change (a1 frags in regs, a0 in LDS) was good:
// LDS frag reads 12->4 per tile, occ 41%, no spill.
// R13 keeps: hybrid placement (a1 regs / a0 LDS), layer-3 parallel accums,
// CHUNK=4, launch_bounds(256,5).
// R13 reverts: tanh back to trans-pipe sig_r with the R9-validated folds
// (2*log2(e) into fragments, 1-2r affine into the W2 dot).

#define N_STATES 16
#define CHUNK    4
#define TANH_SCALE 2.885390081777927f   // 2*log2(e)

typedef _Float16 f16x8 __attribute__((ext_vector_type(8)));
typedef float    f32x4 __attribute__((ext_vector_type(4)));

__device__ __forceinline__ unsigned int pack_f16(float a, float b) {
    auto p = __builtin_amdgcn_cvt_pkrtz(a, b);          // __fp16 ext_vector(2)
    union { decltype(p) h; unsigned int u; } cv{p};
    return cv.u;
}
__device__ __forceinline__ f16x8 u4_to_h8(uint4 v) {
    union { uint4 u; f16x8 h; } x; x.u = v; return x.h;
}
__device__ __forceinline__ uint4 h8_to_u4(f16x8 h) {
    union { f16x8 h; uint4 u; } x; x.h = h; return x.u;
}

// ps = 2*log2(e)*x (pre-scaled via weight fold); r = 1/(e^{2x}+1); tanh = 1-2r.
// exp2/rcp issue on the transcendental pipe (overlaps main VALU — R12 lesson).
__device__ __forceinline__ float sig_r(float ps) {
    float e = __builtin_amdgcn_exp2f(ps);
    return __builtin_amdgcn_rcpf(e + 1.0f);
}
__device__ __forceinline__ float tanh_from_scaled(float ps) {
    return __builtin_fmaf(-2.0f, sig_r(ps), 1.0f);
}

__global__ __launch_bounds__(256, 5) void fans_mfma_kernel(
    const float* __restrict__ x_f, const float* __restrict__ x_b,
    const float* __restrict__ u,   const float* __restrict__ W0,
    const float* __restrict__ W1,  const float* __restrict__ W2,
    float* __restrict__ out)
{
    __shared__ __align__(16) uint4 zplA[256];              // 4 KB: z dwords 0..3
    __shared__ __align__(16) uint2 zplB[256];              // 2 KB: u pair
    __shared__ __align__(16) unsigned int Hd[4][16][36];   // 9 KB, stride 144B
    __shared__ __align__(16) uint4 sA0[4][32];             // 2 KB: [t][q*16+c], q<2

    const int s   = blockIdx.y;
    const int tid = threadIdx.x;
    const int b0  = blockIdx.x * (256 * CHUNK);

    const int lid = tid & 63;
    const int w   = tid >> 6;     // wave id; wave w owns local rows [64w,64w+64)
    const int c   = lid & 15;
    const int q   = lid >> 4;

    // ---- wave 0 stages layer-1 fragments into LDS (identical across waves) ----
    if (tid < 64 && q < 2) {
        // A[m = feat 16t+c][k = 8q+j] = W0[s][feat][k]*SCALE, k<12 else 0
        const float* w0s = W0 + s * 768;
        #pragma unroll
        for (int t = 0; t < 4; ++t) {
            f16x8 v;
            #pragma unroll
            for (int j = 0; j < 8; ++j) {
                const int k = 8 * q + j;
                v[j] = (_Float16)((k < 12) ? w0s[(16 * t + c) * 12 + k] * TANH_SCALE : 0.0f);
            }
            sA0[t][lid] = h8_to_u4(v);                  // lid = q*16+c < 32
        }
    }

    // ---- layer-2 fragments in registers (8 x f16x8 = 32 regs) ----
    // A[m = feat_out 16t+c][k = 32ks+8q+j] = W1[s][o][h]*SCALE
    f16x8 a1[2][4];
    {
        const float* w1s = W1 + s * 4096;
        #pragma unroll
        for (int ks = 0; ks < 2; ++ks) {
            #pragma unroll
            for (int t = 0; t < 4; ++t) {
                const float4* p = (const float4*)(w1s + (16 * t + c) * 64 + 32 * ks + 8 * q);
                const float4 v0 = p[0], v1 = p[1];
                a1[ks][t] = (f16x8){(_Float16)(v0.x * TANH_SCALE), (_Float16)(v0.y * TANH_SCALE),
                                    (_Float16)(v0.z * TANH_SCALE), (_Float16)(v0.w * TANH_SCALE),
                                    (_Float16)(v1.x * TANH_SCALE), (_Float16)(v1.y * TANH_SCALE),
                                    (_Float16)(v1.z * TANH_SCALE), (_Float16)(v1.w * TANH_SCALE)};
            }
        }
    }
    // W2 fold: dx = sum(w2) + sum_o r_o * (-2*w2_o). Lane holds feats 16t+4q+r.
    float w2n[16];
    float sumw2 = 0.0f;
    {
        const float* w2s = W2 + s * 64;
        #pragma unroll
        for (int t = 0; t < 4; ++t)
            #pragma unroll
            for (int r = 0; r < 4; ++r) {
                const float v = w2s[16 * t + 4 * q + r];
                w2n[4 * t + r] = -2.0f * v;
                sumw2 += v;
            }
    }

    __syncthreads();   // one barrier per block: sA0 staging visible

    const int wrap = (s > 8) ? (s - 8) : 0;   // IDX[s] = {0..wrap-1}++{s..15}

    #pragma unroll 1
    for (int ch = 0; ch < CHUNK; ++ch) {
        const int rbase = b0 + ch * 256;

        // ---- phase 1: gather z for own row, pack, write planes ----
        {
            const int row = rbase + tid;
            float zs[8];
            #pragma unroll
            for (int j = 0; j < 8; ++j) {
                const int idx = (j < wrap) ? j : (s + j - wrap);  // uniform
                zs[j] = (idx < 8) ? x_f[row * 8 + idx] : x_b[row * 8 + (idx - 8)];
            }
            const float4 uv = *(const float4*)(u + row * 4);
            zplA[tid] = make_uint4(pack_f16(zs[0], zs[1]), pack_f16(zs[2], zs[3]),
                                   pack_f16(zs[4], zs[5]), pack_f16(zs[6], zs[7]));
            zplB[tid] = make_uint2(pack_f16(uv.x, uv.y), pack_f16(uv.z, uv.w));
        }
        // No barrier: wave w reads only rows [64w,64w+64) which it wrote itself.

        // ---- phase 2: 4 M-tiles of 16 rows (own wave's rows only) ----
        #pragma unroll
        for (int m = 0; m < 4; ++m) {
            const int rowb = 64 * w + 16 * m;

            // z B-frag: B[k = 8q+j][n = row c]; k>=12 zero
            f16x8 zf = {0, 0, 0, 0, 0, 0, 0, 0};
            if (q == 0) {
                zf = u4_to_h8(zplA[rowb + c]);
            } else if (q == 1) {
                const uint2 b = zplB[rowb + c];
                zf = u4_to_h8(make_uint4(b.x, b.y, 0u, 0u));
            }

            // layer 1: C[row = feat 16t+4q+r][col = batch row c], pre-scaled
            f32x4 c1[4];
            #pragma unroll
            for (int t = 0; t < 4; ++t) {
                f16x8 a0t = {0, 0, 0, 0, 0, 0, 0, 0};
                if (q < 2) a0t = u4_to_h8(sA0[t][lid]);
                c1[t] = __builtin_amdgcn_mfma_f32_16x16x32_f16(
                    a0t, zf, (f32x4){0.f, 0.f, 0.f, 0.f}, 0, 0, 0);
            }

            // tanh -> pack -> LDS: dword P = 8t+2q holds feats (16t+4q, +1)
            #pragma unroll
            for (int t = 0; t < 4; ++t) {
                *(uint2*)&Hd[w][c][8 * t + 2 * q] =
                    make_uint2(pack_f16(tanh_from_scaled(c1[t][0]), tanh_from_scaled(c1[t][1])),
                               pack_f16(tanh_from_scaled(c1[t][2]), tanh_from_scaled(c1[t][3])));
            }

            // layer 2: B-frag[k = 32ks+8q+j][n = c] = Hd dwords 16ks+4q+0..3
            f32x4 c2[4] = {{0.f, 0.f, 0.f, 0.f}, {0.f, 0.f, 0.f, 0.f},
                           {0.f, 0.f, 0.f, 0.f}, {0.f, 0.f, 0.f, 0.f}};
            #pragma unroll
            for (int ks = 0; ks < 2; ++ks) {
                const f16x8 hb = u4_to_h8(*(const uint4*)&Hd[w][c][16 * ks + 4 * q]);
                #pragma unroll
                for (int t = 0; t < 4; ++t)
                    c2[t] = __builtin_amdgcn_mfma_f32_16x16x32_f16(a1[ks][t], hb, c2[t], 0, 0, 0);
            }

            // layer 3: acc = sum(w2) + sum r*(-2w2); 4 parallel accums
            float ar0 = sumw2, ar1 = 0.f, ar2 = 0.f, ar3 = 0.f;
            #pragma unroll
            for (int t = 0; t < 4; ++t) {
                ar0 = __builtin_fmaf(sig_r(c2[t][0]), w2n[4 * t + 0], ar0);
                ar1 = __builtin_fmaf(sig_r(c2[t][1]), w2n[4 * t + 1], ar1);
                ar2 = __builtin_fmaf(sig_r(c2[t][2]), w2n[4 * t + 2], ar2);
                ar3 = __builtin_fmaf(sig_r(c2[t][3]), w2n[4 * t + 3], ar3);
            }
            float acc = (ar0 + ar1) + (ar2 + ar3);
            acc += __shfl_xor(acc, 16);
            acc += __shfl_xor(acc, 32);

            if (lid < 16)
                out[(rbase + rowb + lid) * N_STATES + s] = acc;
        }
    }
}

extern "C" void kernel_launch(void* const* d_in, const int* in_sizes, int n_in,
                              void* d_out, int out_size, void* d_ws, size_t ws_size,
                              hipStream_t stream) {
    const float* x_f = (const float*)d_in[0];
    const float* x_b = (const float*)d_in[1];
    const float* u   = (const float*)d_in[2];
    const float* W0  = (const float*)d_in[3];
    const float* W1  = (const float*)d_in[4];
    const float* W2  = (const float*)d_in[5];
    float* out = (float*)d_out;

    const int nb = in_sizes[0] / 8;                 // 131072 = 128 * 1024
    dim3 grid(nb / (256 * CHUNK), N_STATES);        // (128, 16) = 2048 blocks
    fans_mfma_kernel<<<grid, 256, 0, stream>>>(x_f, x_b, u, W0, W1, W2, out);
}

// Round 14
// 139.130 us; speedup vs baseline: 1.0553x; 1.0553x over previous
//
#include <hip/hip_runtime.h>

// FANS: B=131072 rows x 16 states, MLP 12->64->64->1 with tanh, fp32 in/out.
// R14. Cross-round matrix (R9/R11 ~83 vs R12/R13 ~90-92) resolved:
//  - CHUNK=4 + all-thread a1 gather costs ~8us setup per se -> CHUNK=8 back.
//  - The ~83us plateau is tanh work (~500 cyc/tile on either trans or f32-
//    poly route). New route: PACKED-f16 tanh (v_pk_fma_f16, 2 lanes/instr,
//    full-rate) — H is already f16-rounded for the MFMA B-frag, so f16 poly
//    eval adds only ~1e-3 on h (attenuated sqrt(64)*0.05 per later dot).
//    Layer-3 dot via v_dot2_f32_f16 (f32 accumulate, 1 instr/pair).
//  - Hybrid frags kept (a0 in LDS wave-0-staged, a1 in 32 regs); w2 as 8
//    packed-f16 regs. No TANH_SCALE folds (poly takes raw x).
// Tanh budget: 16 pairs/tile x ~8 pk-instrs ~ 130 full-rate instrs vs R12's
// ~224 scalar-poly; trans pipe idle. Predict dur 83 -> 65-75us.

#define N_STATES 16
#define CHUNK    8

typedef _Float16 f16x8 __attribute__((ext_vector_type(8)));
typedef float    f32x4 __attribute__((ext_vector_type(4)));
typedef __fp16   h2    __attribute__((ext_vector_type(2)));   // cvt_pkrtz type

__device__ __forceinline__ h2 pack2(float a, float b) {
    return __builtin_amdgcn_cvt_pkrtz(a, b);    // v_cvt_pkrtz_f16_f32
}
__device__ __forceinline__ unsigned int h2_bits(h2 v) {
    union { h2 h; unsigned int u; } x; x.h = v; return x.u;
}
__device__ __forceinline__ f16x8 u4_to_h8(uint4 v) {
    union { uint4 u; f16x8 h; } x; x.u = v; return x.h;
}
__device__ __forceinline__ uint4 h8_to_u4(f16x8 h) {
    union { f16x8 h; uint4 u; } x; x.h = h; return x.u;
}

// Packed-f16 tanh: xc = clamp(x, +-1.25); tanh ~ xc * P(xc^2), deg-4 P
// (Chebyshev interpolant, |err| <= 3e-5 in f32; f16 eval adds ~1e-3 — h is
// f16-rounded for the MFMA fragment anyway). All ops v_pk_* full-rate.
__device__ __forceinline__ h2 tanh_pk(h2 x) {
    const h2 hi = {(__fp16)1.25f, (__fp16)1.25f};
    const h2 lo = {(__fp16)-1.25f, (__fp16)-1.25f};
    x = __builtin_elementwise_min(__builtin_elementwise_max(x, lo), hi);
    h2 s = x * x;
    const h2 c4 = {(__fp16)0.00598591f, (__fp16)0.00598591f};
    const h2 c3 = {(__fp16)-0.03807894f, (__fp16)-0.03807894f};
    const h2 c2 = {(__fp16)0.12576901f, (__fp16)0.12576901f};
    const h2 c1 = {(__fp16)-0.33203310f, (__fp16)-0.33203310f};
    const h2 c0 = {(__fp16)0.99998110f, (__fp16)0.99998110f};
    h2 p = s * c4 + c3;     // v_pk_fma_f16 (fp-contract)
    p = s * p + c2;
    p = s * p + c1;
    p = s * p + c0;
    return x * p;
}

__global__ __launch_bounds__(256, 4) void fans_mfma_kernel(
    const float* __restrict__ x_f, const float* __restrict__ x_b,
    const float* __restrict__ u,   const float* __restrict__ W0,
    const float* __restrict__ W1,  const float* __restrict__ W2,
    float* __restrict__ out)
{
    __shared__ __align__(16) uint4 zplA[256];              // 4 KB: z dwords 0..3
    __shared__ __align__(16) uint2 zplB[256];              // 2 KB: u pair
    __shared__ __align__(16) unsigned int Hd[4][16][36];   // 9 KB, stride 144B
    __shared__ __align__(16) uint4 sA0[4][32];             // 2 KB: [t][q*16+c], q<2

    const int s   = blockIdx.y;
    const int tid = threadIdx.x;
    const int b0  = blockIdx.x * (256 * CHUNK);

    const int lid = tid & 63;
    const int w   = tid >> 6;     // wave id; wave w owns local rows [64w,64w+64)
    const int c   = lid & 15;
    const int q   = lid >> 4;

    // ---- wave 0 stages layer-1 fragments into LDS (identical across waves) ----
    if (tid < 64 && q < 2) {
        // A[m = feat 16t+c][k = 8q+j] = W0[s][feat][k], k<12 else 0
        const float* w0s = W0 + s * 768;
        #pragma unroll
        for (int t = 0; t < 4; ++t) {
            f16x8 v;
            #pragma unroll
            for (int j = 0; j < 8; ++j) {
                const int k = 8 * q + j;
                v[j] = (_Float16)((k < 12) ? w0s[(16 * t + c) * 12 + k] : 0.0f);
            }
            sA0[t][lid] = h8_to_u4(v);                  // lid = q*16+c < 32
        }
    }

    // ---- layer-2 fragments in registers (8 x f16x8 = 32 regs) ----
    // A[m = feat_out 16t+c][k = 32ks+8q+j] = W1[s][o][h]
    f16x8 a1[2][4];
    {
        const float* w1s = W1 + s * 4096;
        #pragma unroll
        for (int ks = 0; ks < 2; ++ks) {
            #pragma unroll
            for (int t = 0; t < 4; ++t) {
                const float4* p = (const float4*)(w1s + (16 * t + c) * 64 + 32 * ks + 8 * q);
                const float4 v0 = p[0], v1 = p[1];
                a1[ks][t] = (f16x8){(_Float16)v0.x, (_Float16)v0.y, (_Float16)v0.z, (_Float16)v0.w,
                                    (_Float16)v1.x, (_Float16)v1.y, (_Float16)v1.z, (_Float16)v1.w};
            }
        }
    }
    // W2 as packed f16 pairs: w2p[2t+u] = (w2[16t+4q+2u], w2[16t+4q+2u+1])
    h2 w2p[8];
    {
        const float* w2s = W2 + s * 64;
        #pragma unroll
        for (int t = 0; t < 4; ++t) {
            const int base = 16 * t + 4 * q;
            w2p[2 * t + 0] = pack2(w2s[base + 0], w2s[base + 1]);
            w2p[2 * t + 1] = pack2(w2s[base + 2], w2s[base + 3]);
        }
    }

    __syncthreads();   // one barrier per block: sA0 staging visible

    const int wrap = (s > 8) ? (s - 8) : 0;   // IDX[s] = {0..wrap-1}++{s..15}

    #pragma unroll 1
    for (int ch = 0; ch < CHUNK; ++ch) {
        const int rbase = b0 + ch * 256;

        // ---- phase 1: gather z for own row, pack, write planes ----
        {
            const int row = rbase + tid;
            float zs[8];
            #pragma unroll
            for (int j = 0; j < 8; ++j) {
                const int idx = (j < wrap) ? j : (s + j - wrap);  // uniform
                zs[j] = (idx < 8) ? x_f[row * 8 + idx] : x_b[row * 8 + (idx - 8)];
            }
            const float4 uv = *(const float4*)(u + row * 4);
            zplA[tid] = make_uint4(h2_bits(pack2(zs[0], zs[1])), h2_bits(pack2(zs[2], zs[3])),
                                   h2_bits(pack2(zs[4], zs[5])), h2_bits(pack2(zs[6], zs[7])));
            zplB[tid] = make_uint2(h2_bits(pack2(uv.x, uv.y)), h2_bits(pack2(uv.z, uv.w)));
        }
        // No barrier: wave w reads only rows [64w,64w+64) which it wrote itself.

        // ---- phase 2: 4 M-tiles of 16 rows (own wave's rows only) ----
        #pragma unroll
        for (int m = 0; m < 4; ++m) {
            const int rowb = 64 * w + 16 * m;

            // z B-frag: B[k = 8q+j][n = row c]; k>=12 zero
            f16x8 zf = {0, 0, 0, 0, 0, 0, 0, 0};
            if (q == 0) {
                zf = u4_to_h8(zplA[rowb + c]);
            } else if (q == 1) {
                const uint2 b = zplB[rowb + c];
                zf = u4_to_h8(make_uint4(b.x, b.y, 0u, 0u));
            }

            // layer 1: C[row = feat 16t+4q+r][col = batch row c]
            f32x4 c1[4];
            #pragma unroll
            for (int t = 0; t < 4; ++t) {
                f16x8 a0t = {0, 0, 0, 0, 0, 0, 0, 0};
                if (q < 2) a0t = u4_to_h8(sA0[t][lid]);
                c1[t] = __builtin_amdgcn_mfma_f32_16x16x32_f16(
                    a0t, zf, (f32x4){0.f, 0.f, 0.f, 0.f}, 0, 0, 0);
            }

            // packed-f16 tanh -> LDS: dword P = 8t+2q holds feats (16t+4q, +1)
            #pragma unroll
            for (int t = 0; t < 4; ++t) {
                const h2 th0 = tanh_pk(pack2(c1[t][0], c1[t][1]));
                const h2 th1 = tanh_pk(pack2(c1[t][2], c1[t][3]));
                *(uint2*)&Hd[w][c][8 * t + 2 * q] = make_uint2(h2_bits(th0), h2_bits(th1));
            }

            // layer 2: B-frag[k = 32ks+8q+j][n = c] = Hd dwords 16ks+4q+0..3
            f32x4 c2[4] = {{0.f, 0.f, 0.f, 0.f}, {0.f, 0.f, 0.f, 0.f},
                           {0.f, 0.f, 0.f, 0.f}, {0.f, 0.f, 0.f, 0.f}};
            #pragma unroll
            for (int ks = 0; ks < 2; ++ks) {
                const f16x8 hb = u4_to_h8(*(const uint4*)&Hd[w][c][16 * ks + 4 * q]);
                #pragma unroll
                for (int t = 0; t < 4; ++t)
                    c2[t] = __builtin_amdgcn_mfma_f32_16x16x32_f16(a1[ks][t], hb, c2[t], 0, 0, 0);
            }

            // layer 3: packed tanh + v_dot2_f32_f16 accumulate (f32 accum)
            float ar0 = 0.f, ar1 = 0.f;
            #pragma unroll
            for (int t = 0; t < 4; ++t) {
                const h2 th0 = tanh_pk(pack2(c2[t][0], c2[t][1]));
                const h2 th1 = tanh_pk(pack2(c2[t][2], c2[t][3]));
                ar0 = __builtin_amdgcn_fdot2(th0, w2p[2 * t + 0], ar0, false);
                ar1 = __builtin_amdgcn_fdot2(th1, w2p[2 * t + 1], ar1, false);
            }
            float acc = ar0 + ar1;
            acc += __shfl_xor(acc, 16);
            acc += __shfl_xor(acc, 32);

            if (lid < 16)
                out[(rbase + rowb + lid) * N_STATES + s] = acc;
        }
    }
}

extern "C" void kernel_launch(void* const* d_in, const int* in_sizes, int n_in,
                              void* d_out, int out_size, void* d_ws, size_t ws_size,
                              hipStream_t stream) {
    const float* x_f = (const float*)d_in[0];
    const float* x_b = (const float*)d_in[1];
    const float* u   = (const float*)d_in[2];
    const float* W0  = (const float*)d_in[3];
    const float* W1  = (const float*)d_in[4];
    const float* W2  = (const float*)d_in[5];
    float* out = (float*)d_out;

    const int nb = in_sizes[0] / 8;                 // 131072 = 64 * 2048
    dim3 grid(nb / (256 * CHUNK), N_STATES);        // (64, 16) = 1024 blocks
    fans_mfma_kernel<<<grid, 256, 0, stream>>>(x_f, x_b, u, W0, W1, W2, out);
}